// Round 18
// baseline (93.564 us; speedup 1.0000x reference)
//
#include <hip/hip_runtime.h>
#include <stdint.h>

#define HH 2048
#define WW 2048
#define TILE_W 64
#define TILE_H 32
#define HALO 3
#define ROWS_T (TILE_H + 2 * HALO)   // 38
#define LDSW 76                      // 72 cols used + 4 pad
#define SC_BLOCK 256
#define SC_GRID 1024
#define SCVPT 8                      // uint4/thread in the full scan
#define MAXBINS 4096
#define HSPREAD 16                   // flush-contention spread (slot-major)
#define CAPT 16                      // per-thread candidate capacity (Poisson mean ~1)
#define NSAMP 65536
#define RLO 31744                    // 32768 - 1024  (8 sigma in quantile space)
#define RHI 33792                    // 32768 + 1024

typedef float f4v __attribute__((ext_vector_type(4)));

// Monotone map: float bits -> uint32 such that uint order == float order.
__device__ __forceinline__ uint32_t map_f32(uint32_t b) {
    uint32_t mask = ((int32_t)b >> 31) | 0x80000000u;
    return b ^ mask;
}
__device__ __forceinline__ float unmap_f32(uint32_t u) {
    uint32_t b = (u & 0x80000000u) ? (u ^ 0x80000000u) : ~u;
    return __uint_as_float(b);
}

// state: [0]=median(mapped) [1]=b1 [2]=p_lo [3]=p_hi [4]=k_in_bucket [5]=C [6]=below [7]=C2

// Block 0: sample first 65536 elements, pick 12-bit bucket range covering the
// median with ±8-sigma quantile margin. Blocks 1..16: zero ghist (slot copies).
__global__ void __launch_bounds__(1024)
init_sample_kernel(const uint4* __restrict__ in, uint32_t* __restrict__ ghist,
                   uint32_t* __restrict__ state) {
    int tid = threadIdx.x;
    if (blockIdx.x > 0) {
        int chunk = MAXBINS * HSPREAD / 16;          // 4096 words per block
        int base = (blockIdx.x - 1) * chunk;
        for (int i = tid; i < chunk; i += 1024) ghist[base + i] = 0;
        return;
    }
    __shared__ uint32_t lh[MAXBINS];
    __shared__ uint32_t sums[256];
    if (tid < 8) state[tid] = 0u;
    for (int i = tid; i < MAXBINS; i += 1024) lh[i] = 0;
    __syncthreads();

    uint4 v[NSAMP / 4 / 1024];                       // 16 uint4 per thread
    #pragma unroll
    for (int j = 0; j < NSAMP / 4 / 1024; ++j) v[j] = in[tid + j * 1024];
    #pragma unroll
    for (int j = 0; j < NSAMP / 4 / 1024; ++j) {
        atomicAdd(&lh[map_f32(v[j].x) >> 20], 1u);
        atomicAdd(&lh[map_f32(v[j].y) >> 20], 1u);
        atomicAdd(&lh[map_f32(v[j].z) >> 20], 1u);
        atomicAdd(&lh[map_f32(v[j].w) >> 20], 1u);
    }
    __syncthreads();
    if (tid < 256) {
        uint32_t s = 0;
        #pragma unroll
        for (int i = 0; i < 16; ++i) s += lh[tid * 16 + i];
        sums[tid] = s;
    }
    __syncthreads();
    if (tid < 256) {
        uint32_t local[16];
        uint32_t s = 0;
        #pragma unroll
        for (int i = 0; i < 16; ++i) { local[i] = lh[tid * 16 + i]; s += local[i]; }
        uint32_t excl = 0;
        for (int i = 0; i < tid; ++i) excl += sums[i];
        if (RLO >= excl && RLO < excl + s) {
            uint32_t cum = excl;
            #pragma unroll
            for (int i = 0; i < 16; ++i) {
                if (RLO >= cum && RLO < cum + local[i]) state[2] = (uint32_t)(tid * 16 + i);
                cum += local[i];
            }
        }
        if (RHI >= excl && RHI < excl + s) {
            uint32_t cum = excl;
            #pragma unroll
            for (int i = 0; i < 16; ++i) {
                if (RHI >= cum && RHI < cum + local[i]) state[3] = (uint32_t)(tid * 16 + i);
                cum += local[i];
            }
        }
    }
}

// ONE full scan, atomic-free hot loop: exact count of p<p_lo + per-thread
// LDS-buffered compaction of p in [p_lo,p_hi]. No in-scan histogram.
__global__ void __launch_bounds__(SC_BLOCK)
scan_kernel(const uint4* __restrict__ in, int nvec,
            uint32_t* __restrict__ cand,
            uint32_t* __restrict__ state) {
    __shared__ uint32_t lcand[CAPT * SC_BLOCK];  // 16 KB, slot j*256+tid
    __shared__ uint32_t pscan[SC_BLOCK];
    __shared__ uint32_t lbelow, s_gbase;
    int tid = threadIdx.x;
    if (tid == 0) lbelow = 0u;
    uint32_t p_lo = state[2], p_hi = state[3];
    __syncthreads();

    int total = SC_GRID * SC_BLOCK;
    int i0 = blockIdx.x * SC_BLOCK + tid;
    uint32_t below = 0;
    uint32_t cnt = 0;

    if (nvec == total * SCVPT) {
        uint4 v[SCVPT];
        #pragma unroll
        for (int j = 0; j < SCVPT; ++j) v[j] = in[i0 + j * total];
        #pragma unroll
        for (int j = 0; j < SCVPT; ++j) {
            uint32_t uu[4] = { map_f32(v[j].x), map_f32(v[j].y),
                               map_f32(v[j].z), map_f32(v[j].w) };
            #pragma unroll
            for (int e = 0; e < 4; ++e) {
                uint32_t u = uu[e];
                uint32_t p = u >> 20;
                below += (p < p_lo) ? 1u : 0u;
                if (p >= p_lo && p <= p_hi) {      // rare (~3%); body is 1 LDS write
                    if (cnt < CAPT) lcand[cnt * SC_BLOCK + tid] = u;
                    cnt++;
                }
            }
        }
    } else {
        for (int i = i0; i < nvec; i += total) {
            uint4 v = in[i];
            uint32_t uu[4] = { map_f32(v.x), map_f32(v.y), map_f32(v.z), map_f32(v.w) };
            #pragma unroll
            for (int e = 0; e < 4; ++e) {
                uint32_t u = uu[e];
                uint32_t p = u >> 20;
                below += (p < p_lo) ? 1u : 0u;
                if (p >= p_lo && p <= p_hi) {
                    if (cnt < CAPT) lcand[cnt * SC_BLOCK + tid] = u;
                    cnt++;
                }
            }
        }
    }
    if (cnt > CAPT) cnt = CAPT;                    // P ~ 1e-10
    atomicAdd(&lbelow, below);
    pscan[tid] = cnt;
    __syncthreads();

    // Hillis-Steele inclusive scan over 256 counts
    for (int off = 1; off < SC_BLOCK; off <<= 1) {
        uint32_t v2 = (tid >= off) ? pscan[tid - off] : 0u;
        __syncthreads();
        pscan[tid] += v2;
        __syncthreads();
    }
    uint32_t excl = pscan[tid] - cnt;
    uint32_t btotal = pscan[SC_BLOCK - 1];

    if (tid == 0) {
        s_gbase = atomicAdd(&state[5], btotal);
        atomicAdd(&state[6], lbelow);
    }
    __syncthreads();
    uint32_t gb = s_gbase;
    for (uint32_t j = 0; j < cnt; ++j) cand[gb + excl + j] = lcand[j * SC_BLOCK + tid];
}

// Histogram of the ~300K compacted candidates (12-bit p), slot-spread flush.
__global__ void __launch_bounds__(256)
cand_hist_kernel(const uint32_t* __restrict__ cand,
                 uint32_t* __restrict__ ghist,
                 const uint32_t* __restrict__ state) {
    __shared__ uint32_t lh[MAXBINS];
    int tid = threadIdx.x;
    for (int i = tid; i < MAXBINS; i += 256) lh[i] = 0;
    __syncthreads();
    uint32_t C = state[5];
    uint32_t stride = gridDim.x * 256;
    for (uint32_t i = blockIdx.x * 256 + tid; i < C; i += stride)
        atomicAdd(&lh[cand[i] >> 20], 1u);
    __syncthreads();
    int slot = blockIdx.x & (HSPREAD - 1);
    uint32_t* gslot = ghist + (size_t)slot * MAXBINS;
    for (int b = tid; b < MAXBINS; b += 256) {
        uint32_t s = lh[b];
        if (s) atomicAdd(&gslot[b], s);
    }
}

// Single block: sum slot copies, pick exact bucket for rank k' = k0 - below.
__global__ void __launch_bounds__(256)
bucket_select_kernel(uint32_t* __restrict__ hist, uint32_t* __restrict__ state,
                     uint32_t k0) {
    __shared__ uint32_t sums[256];
    int tid = threadIdx.x;
    uint32_t k = k0 - state[6];
    uint32_t local[16];
    #pragma unroll
    for (int i = 0; i < 16; ++i) local[i] = 0;
    for (int sp = 0; sp < HSPREAD; ++sp) {
        const uint4* h = (const uint4*)(hist + (size_t)sp * MAXBINS + tid * 16);
        #pragma unroll
        for (int i = 0; i < 4; ++i) {
            uint4 v = h[i];
            local[4 * i + 0] += v.x;
            local[4 * i + 1] += v.y;
            local[4 * i + 2] += v.z;
            local[4 * i + 3] += v.w;
        }
    }
    uint32_t s = 0;
    #pragma unroll
    for (int i = 0; i < 16; ++i) s += local[i];
    sums[tid] = s;
    __syncthreads();
    uint32_t excl = 0;
    for (int i = 0; i < tid; ++i) excl += sums[i];
    if (k >= excl && k < excl + s) {
        uint32_t cum = excl;
        #pragma unroll
        for (int i = 0; i < 16; ++i) {
            if (k >= cum && k < cum + local[i]) {
                state[1] = (uint32_t)(tid * 16 + i);
                state[4] = k - cum;
            }
            cum += local[i];
        }
    }
}

// Grid compact over the candidate array (L2-hot): keep exact-bucket elements.
__global__ void __launch_bounds__(256)
compact2_kernel(const uint32_t* __restrict__ cand, uint32_t* __restrict__ cand2,
                uint32_t* __restrict__ state) {
    uint32_t C = state[5];
    uint32_t b1 = state[1];
    int tid = threadIdx.x;
    int lane = tid & 63;
    uint64_t lt = ((uint64_t)1 << lane) - 1;
    uint32_t stride = gridDim.x * blockDim.x;
    for (uint32_t i = blockIdx.x * blockDim.x + tid; i < C; i += stride) {
        uint32_t u = cand[i];
        bool p = (u >> 20) == b1;
        uint64_t ball = __ballot(p);
        if (ball) {
            int leader = __ffsll((unsigned long long)ball) - 1;
            uint32_t base = 0;
            if (lane == leader) base = atomicAdd(&state[7], (uint32_t)__popcll(ball));
            base = __shfl(base, leader);
            if (p) cand2[base + __popcll(ball & lt)] = u;
        }
    }
}

// Single block: exact rank within the bucket (two radix passes over ~2-3K elems).
__global__ void __launch_bounds__(1024)
final2_kernel(const uint32_t* __restrict__ cand2, uint32_t* __restrict__ state) {
    __shared__ uint32_t lh[MAXBINS];
    __shared__ uint32_t sums[256];
    __shared__ uint32_t s_p2, s_k2;
    int tid = threadIdx.x;
    uint32_t C2 = state[7];
    uint32_t prefix = state[1] << 20;
    uint32_t k = state[4];
    for (int i = tid; i < MAXBINS; i += 1024) lh[i] = 0;
    __syncthreads();

    // Pass A: bits [8,20)
    for (uint32_t i = tid; i < C2; i += 1024)
        atomicAdd(&lh[(cand2[i] >> 8) & 4095u], 1u);
    __syncthreads();
    if (tid < 256) {
        uint32_t s = 0;
        #pragma unroll
        for (int i = 0; i < 16; ++i) s += lh[tid * 16 + i];
        sums[tid] = s;
    }
    __syncthreads();
    if (tid < 256) {
        uint32_t local[16];
        uint32_t s = 0;
        #pragma unroll
        for (int i = 0; i < 16; ++i) { local[i] = lh[tid * 16 + i]; s += local[i]; }
        uint32_t excl = 0;
        for (int i = 0; i < tid; ++i) excl += sums[i];
        if (k >= excl && k < excl + s) {
            uint32_t cum = excl;
            #pragma unroll
            for (int i = 0; i < 16; ++i) {
                if (k >= cum && k < cum + local[i]) {
                    s_p2 = prefix | ((uint32_t)(tid * 16 + i) << 8);
                    s_k2 = k - cum;
                }
                cum += local[i];
            }
        }
    }
    __syncthreads();

    // Pass B: bits [0,8)
    for (int i = tid; i < 256; i += 1024) lh[i] = 0;
    __syncthreads();
    uint32_t pfx = s_p2;
    uint32_t kb = s_k2;
    for (uint32_t i = tid; i < C2; i += 1024) {
        uint32_t u = cand2[i];
        if ((u & 0xFFFFFF00u) == pfx) atomicAdd(&lh[u & 255u], 1u);
    }
    __syncthreads();
    if (tid < 256) sums[tid] = lh[tid];
    __syncthreads();
    if (tid < 256) {
        uint32_t cnt = sums[tid];
        uint32_t excl = 0;
        for (int i = 0; i < tid; ++i) excl += sums[i];
        if (kb >= excl && kb < excl + cnt) {
            state[0] = pfx | (uint32_t)tid;   // exact mapped median
        }
    }
}

// Fused threshold + 7x7 maxpool (separable) + compare + write (round-17 body).
__global__ void __launch_bounds__(256)
nms_kernel(const float* __restrict__ x, float* __restrict__ out,
           const uint32_t* __restrict__ state) {
    __shared__ float t_lds[ROWS_T][LDSW];        // 38 x 76
    __shared__ float h_lds[ROWS_T][TILE_W + 1];  // 38 x 65
    float med = unmap_f32(state[0]);

    int plane = blockIdx.z;
    int tr0 = blockIdx.y * TILE_H;
    int tc0 = blockIdx.x * TILE_W;
    const float* px = x + (size_t)plane * HH * WW;
    float* pout = out + (size_t)plane * HH * WW;
    int tid = threadIdx.x;

    bool interior = (blockIdx.x >= 1) && (blockIdx.x <= (WW / TILE_W) - 2) &&
                    (blockIdx.y >= 1) && (blockIdx.y <= (HH / TILE_H) - 2);
    if (interior) {
        const float4* pv = (const float4*)(px + (size_t)(tr0 - 3) * WW + (tc0 - 4));
        for (int i = tid; i < ROWS_T * 18; i += 256) {
            int r = i / 18, v = i - r * 18;
            float4 d = pv[(size_t)r * (WW / 4) + v];
            int c = v * 4;
            t_lds[r][c + 0] = (d.x < med) ? 0.f : d.x;
            t_lds[r][c + 1] = (d.y < med) ? 0.f : d.y;
            t_lds[r][c + 2] = (d.z < med) ? 0.f : d.z;
            t_lds[r][c + 3] = (d.w < med) ? 0.f : d.w;
        }
    } else {
        for (int i = tid; i < ROWS_T * 72; i += 256) {
            int r = i / 72, c = i - r * 72;
            int gr = tr0 - 3 + r, gc = tc0 - 4 + c;
            float vv = -INFINITY;
            if (gr >= 0 && gr < HH && gc >= 0 && gc < WW) {
                float xv = px[(size_t)gr * WW + gc];
                vv = (xv < med) ? 0.f : xv;
            }
            t_lds[r][c] = vv;
        }
    }
    __syncthreads();

    for (int i = tid; i < ROWS_T * 16; i += 256) {
        int r = i >> 4, c4 = (i & 15) * 4;
        float t[10];
        #pragma unroll
        for (int j = 0; j < 10; ++j) t[j] = t_lds[r][c4 + 1 + j];
        float mid = fmaxf(fmaxf(t[3], t[4]), fmaxf(t[5], t[6]));
        h_lds[r][c4 + 0] = fmaxf(fmaxf(t[0], t[1]), fmaxf(t[2], mid));
        h_lds[r][c4 + 1] = fmaxf(fmaxf(t[1], t[2]), fmaxf(t[7], mid));
        h_lds[r][c4 + 2] = fmaxf(fmaxf(t[2], t[7]), fmaxf(t[8], mid));
        h_lds[r][c4 + 3] = fmaxf(fmaxf(t[7], t[8]), fmaxf(t[9], mid));
    }
    __syncthreads();

    for (int i = tid; i < (TILE_H / 2) * (TILE_W / 4); i += 256) {
        int pr = i >> 4, c4 = (i & 15) * 4;
        int r0 = pr * 2;
        float sh0 = h_lds[r0 + 1][c4 + 0];
        float sh1 = h_lds[r0 + 1][c4 + 1];
        float sh2 = h_lds[r0 + 1][c4 + 2];
        float sh3 = h_lds[r0 + 1][c4 + 3];
        #pragma unroll
        for (int j = 2; j <= 6; ++j) {
            sh0 = fmaxf(sh0, h_lds[r0 + j][c4 + 0]);
            sh1 = fmaxf(sh1, h_lds[r0 + j][c4 + 1]);
            sh2 = fmaxf(sh2, h_lds[r0 + j][c4 + 2]);
            sh3 = fmaxf(sh3, h_lds[r0 + j][c4 + 3]);
        }
        float a0 = fmaxf(sh0, h_lds[r0][c4 + 0]);
        float a1 = fmaxf(sh1, h_lds[r0][c4 + 1]);
        float a2 = fmaxf(sh2, h_lds[r0][c4 + 2]);
        float a3 = fmaxf(sh3, h_lds[r0][c4 + 3]);
        float b0 = fmaxf(sh0, h_lds[r0 + 7][c4 + 0]);
        float b1 = fmaxf(sh1, h_lds[r0 + 7][c4 + 1]);
        float b2 = fmaxf(sh2, h_lds[r0 + 7][c4 + 2]);
        float b3 = fmaxf(sh3, h_lds[r0 + 7][c4 + 3]);

        float t0 = t_lds[r0 + 3][c4 + 4], t1 = t_lds[r0 + 3][c4 + 5];
        float t2 = t_lds[r0 + 3][c4 + 6], t3 = t_lds[r0 + 3][c4 + 7];
        f4v o;
        o.x = (a0 == t0 && t0 != 0.f) ? t0 : 0.f;
        o.y = (a1 == t1 && t1 != 0.f) ? t1 : 0.f;
        o.z = (a2 == t2 && t2 != 0.f) ? t2 : 0.f;
        o.w = (a3 == t3 && t3 != 0.f) ? t3 : 0.f;
        __builtin_nontemporal_store(o, (f4v*)(pout + (size_t)(tr0 + r0) * WW + (tc0 + c4)));

        t0 = t_lds[r0 + 4][c4 + 4]; t1 = t_lds[r0 + 4][c4 + 5];
        t2 = t_lds[r0 + 4][c4 + 6]; t3 = t_lds[r0 + 4][c4 + 7];
        o.x = (b0 == t0 && t0 != 0.f) ? t0 : 0.f;
        o.y = (b1 == t1 && t1 != 0.f) ? t1 : 0.f;
        o.z = (b2 == t2 && t2 != 0.f) ? t2 : 0.f;
        o.w = (b3 == t3 && t3 != 0.f) ? t3 : 0.f;
        __builtin_nontemporal_store(o, (f4v*)(pout + (size_t)(tr0 + r0 + 1) * WW + (tc0 + c4)));
    }
}

extern "C" void kernel_launch(void* const* d_in, const int* in_sizes, int n_in,
                              void* d_out, int out_size, void* d_ws, size_t ws_size,
                              hipStream_t stream) {
    const float* x = (const float*)d_in[0];
    float* out = (float*)d_out;
    int n = in_sizes[0];                        // 8388608
    uint32_t* ghist = (uint32_t*)d_ws;          // 4096*16 u32 (slot-major)
    uint32_t* state = ghist + MAXBINS * HSPREAD;// 8 u32
    uint32_t* cand = state + 8;                 // in-range candidates
    uint32_t* cand2 = cand + 8388608;           // exact-bucket candidates
    uint32_t k = (uint32_t)((n - 1) / 2);
    int nvec = n / 4;

    init_sample_kernel<<<17, 1024, 0, stream>>>((const uint4*)x, ghist, state);
    scan_kernel<<<SC_GRID, SC_BLOCK, 0, stream>>>((const uint4*)x, nvec, cand, state);
    cand_hist_kernel<<<64, 256, 0, stream>>>(cand, ghist, state);
    bucket_select_kernel<<<1, 256, 0, stream>>>(ghist, state, k);
    compact2_kernel<<<256, 256, 0, stream>>>(cand, cand2, state);
    final2_kernel<<<1, 1024, 0, stream>>>(cand2, state);

    int nplanes = n / (HH * WW);                // 2
    dim3 grid(WW / TILE_W, HH / TILE_H, nplanes);
    nms_kernel<<<grid, 256, 0, stream>>>(x, out, state);
}

// Round 19
// 58.597 us; speedup vs baseline: 1.5968x; 1.5968x over previous
//
#include <hip/hip_runtime.h>
#include <stdint.h>

#define HH 2048
#define WW 2048
#define TILE_W 64
#define TILE_H 32
#define HALO 3
#define ROWS_T (TILE_H + 2 * HALO)   // 38
#define LDSW 76                      // 72 cols used + 4 pad
#define HIST_BLOCK 256
#define HIST_GRID 1024               // hist: proven config (VPT=8, 4 blocks/CU)
#define HVPT 8
#define COMP_GRID 2048               // compact: L3-hot read, 4-deep suffices
#define CVPT 4
#define MAXBINS 4096
#define HSPREAD 16                   // flush-contention spread (slot-major)

typedef float f4v __attribute__((ext_vector_type(4)));

// Monotone map: float bits -> uint32 such that uint order == float order.
__device__ __forceinline__ uint32_t map_f32(uint32_t b) {
    uint32_t mask = ((int32_t)b >> 31) | 0x80000000u;
    return b ^ mask;
}
__device__ __forceinline__ float unmap_f32(uint32_t u) {
    uint32_t b = (u & 0x80000000u) ? (u ^ 0x80000000u) : ~u;
    return __uint_as_float(b);
}

// state: [0]=prefix/median(mapped), [1]=k_remaining, [5]=candidate count
__global__ void init_kernel(uint32_t* hist, uint32_t* state, uint32_t k) {
    int i = blockIdx.x * blockDim.x + threadIdx.x;
    if (i < MAXBINS * HSPREAD) hist[i] = 0;
    if (i < 8) state[i] = 0u;
    if (i == 1) state[1] = k;
}

// Level-0 histogram over top 12 bits; 8 independent uint4 loads in flight.
// Flush spreads each bin over HSPREAD slot-major copies (16 KB apart).
__global__ void __launch_bounds__(HIST_BLOCK)
hist_kernel(const uint4* __restrict__ in, int nvec,
            uint32_t* __restrict__ ghist) {
    __shared__ uint32_t lh[MAXBINS];
    int tid = threadIdx.x;
    for (int i = tid; i < MAXBINS; i += HIST_BLOCK) lh[i] = 0;
    __syncthreads();

    int total = HIST_GRID * HIST_BLOCK;
    int i0 = blockIdx.x * HIST_BLOCK + tid;

    if (nvec == total * HVPT) {
        uint4 v[HVPT];
        #pragma unroll
        for (int j = 0; j < HVPT; ++j) v[j] = in[i0 + j * total];
        #pragma unroll
        for (int j = 0; j < HVPT; ++j) {
            atomicAdd(&lh[map_f32(v[j].x) >> 20], 1u);
            atomicAdd(&lh[map_f32(v[j].y) >> 20], 1u);
            atomicAdd(&lh[map_f32(v[j].z) >> 20], 1u);
            atomicAdd(&lh[map_f32(v[j].w) >> 20], 1u);
        }
    } else {
        for (int i = i0; i < nvec; i += total) {
            uint4 v = in[i];
            atomicAdd(&lh[map_f32(v.x) >> 20], 1u);
            atomicAdd(&lh[map_f32(v.y) >> 20], 1u);
            atomicAdd(&lh[map_f32(v.z) >> 20], 1u);
            atomicAdd(&lh[map_f32(v.w) >> 20], 1u);
        }
    }
    __syncthreads();
    int slot = blockIdx.x & (HSPREAD - 1);
    uint32_t* gslot = ghist + (size_t)slot * MAXBINS;
    for (int b = tid; b < MAXBINS; b += HIST_BLOCK) {
        uint32_t s = lh[b];
        if (s) atomicAdd(&gslot[b], s);
    }
}

// Single block: sum the HSPREAD slot copies (uint4 reads), pick rank-k bucket.
__global__ void __launch_bounds__(256)
select_kernel(uint32_t* __restrict__ hist, uint32_t* __restrict__ state) {
    __shared__ uint32_t sums[256];
    int tid = threadIdx.x;
    uint32_t k = state[1];
    uint32_t local[16];
    #pragma unroll
    for (int i = 0; i < 16; ++i) local[i] = 0;
    for (int sp = 0; sp < HSPREAD; ++sp) {
        const uint4* h = (const uint4*)(hist + (size_t)sp * MAXBINS + tid * 16);
        #pragma unroll
        for (int i = 0; i < 4; ++i) {
            uint4 v = h[i];
            local[4 * i + 0] += v.x;
            local[4 * i + 1] += v.y;
            local[4 * i + 2] += v.z;
            local[4 * i + 3] += v.w;
        }
    }
    uint32_t s = 0;
    #pragma unroll
    for (int i = 0; i < 16; ++i) s += local[i];
    sums[tid] = s;
    __syncthreads();
    uint32_t excl = 0;
    for (int i = 0; i < tid; ++i) excl += sums[i];
    if (k >= excl && k < excl + s) {
        uint32_t cum = excl;
        #pragma unroll
        for (int i = 0; i < 16; ++i) {
            if (k >= cum && k < cum + local[i]) {
                state[0] = ((uint32_t)(tid * 16 + i)) << 20;
                state[1] = k - cum;
            }
            cum += local[i];
        }
    }
}

__device__ __forceinline__ void emit_cand(uint32_t u, uint32_t prefix, int lane,
                                          uint64_t lt, uint32_t* cand,
                                          uint32_t* counter) {
    bool p = (u & 0xFFF00000u) == prefix;
    uint64_t ball = __ballot(p);
    if (ball) {
        int leader = __ffsll((unsigned long long)ball) - 1;
        uint32_t base = 0;
        if (lane == leader) base = atomicAdd(counter, (uint32_t)__popcll(ball));
        base = __shfl(base, leader);
        if (p) cand[base + __popcll(ball & lt)] = u;
    }
}

// Compact all elements whose top-12 mapped bits equal the selected prefix.
__global__ void __launch_bounds__(HIST_BLOCK)
compact_kernel(const uint4* __restrict__ in, int nvec,
               uint32_t* __restrict__ cand,
               uint32_t* __restrict__ state) {
    uint32_t prefix = state[0];
    uint32_t* counter = &state[5];
    int total = COMP_GRID * HIST_BLOCK;
    int tid = threadIdx.x;
    int i0 = blockIdx.x * HIST_BLOCK + tid;
    int lane = tid & 63;
    uint64_t lt = ((uint64_t)1 << lane) - 1;

    if (nvec == total * CVPT) {
        uint4 v[CVPT];
        #pragma unroll
        for (int j = 0; j < CVPT; ++j) v[j] = in[i0 + j * total];
        #pragma unroll
        for (int j = 0; j < CVPT; ++j) {
            emit_cand(map_f32(v[j].x), prefix, lane, lt, cand, counter);
            emit_cand(map_f32(v[j].y), prefix, lane, lt, cand, counter);
            emit_cand(map_f32(v[j].z), prefix, lane, lt, cand, counter);
            emit_cand(map_f32(v[j].w), prefix, lane, lt, cand, counter);
        }
    } else {
        for (int i = i0; i < nvec; i += total) {
            uint4 v = in[i];
            emit_cand(map_f32(v.x), prefix, lane, lt, cand, counter);
            emit_cand(map_f32(v.y), prefix, lane, lt, cand, counter);
            emit_cand(map_f32(v.z), prefix, lane, lt, cand, counter);
            emit_cand(map_f32(v.w), prefix, lane, lt, cand, counter);
        }
    }
}

// Single block: exact k-th smallest among candidates (two radix passes in LDS).
__global__ void __launch_bounds__(1024)
final_select_kernel(const uint32_t* __restrict__ cand,
                    uint32_t* __restrict__ state) {
    __shared__ uint32_t lh[MAXBINS];
    __shared__ uint32_t sums[256];
    __shared__ uint32_t s_prefix, s_k;
    int tid = threadIdx.x;
    uint32_t C = state[5];

    if (tid == 0) { s_prefix = state[0]; s_k = state[1]; }
    for (int i = tid; i < MAXBINS; i += 1024) lh[i] = 0;
    __syncthreads();

    // Pass A: bits [8,20)
    for (uint32_t i = tid; i < C; i += 1024)
        atomicAdd(&lh[(cand[i] >> 8) & 4095u], 1u);
    __syncthreads();
    if (tid < 256) {
        uint32_t local[16];
        uint32_t s = 0;
        #pragma unroll
        for (int i = 0; i < 16; ++i) { local[i] = lh[tid * 16 + i]; s += local[i]; }
        sums[tid] = s;
    }
    __syncthreads();
    if (tid < 256) {
        uint32_t local[16];
        uint32_t s = 0;
        #pragma unroll
        for (int i = 0; i < 16; ++i) { local[i] = lh[tid * 16 + i]; s += local[i]; }
        uint32_t excl = 0;
        for (int i = 0; i < tid; ++i) excl += sums[i];
        uint32_t k = s_k;
        if (k >= excl && k < excl + s) {
            uint32_t cum = excl;
            #pragma unroll
            for (int i = 0; i < 16; ++i) {
                if (k >= cum && k < cum + local[i]) {
                    s_prefix |= ((uint32_t)(tid * 16 + i)) << 8;
                    s_k = k - cum;
                }
                cum += local[i];
            }
        }
    }
    __syncthreads();

    // Pass B: bits [0,8)
    for (int i = tid; i < 256; i += 1024) lh[i] = 0;
    __syncthreads();
    uint32_t pfx = s_prefix;
    for (uint32_t i = tid; i < C; i += 1024) {
        uint32_t u = cand[i];
        if ((u & 0xFFFFFF00u) == pfx) atomicAdd(&lh[u & 255u], 1u);
    }
    __syncthreads();
    if (tid < 256) {
        uint32_t cnt = lh[tid];
        sums[tid] = cnt;
    }
    __syncthreads();
    if (tid < 256) {
        uint32_t cnt = sums[tid];
        uint32_t excl = 0;
        for (int i = 0; i < tid; ++i) excl += sums[i];
        uint32_t k = s_k;
        if (k >= excl && k < excl + cnt) {
            state[0] = pfx | (uint32_t)tid;   // exact mapped median
        }
    }
}

// Fused threshold + 7x7 maxpool (separable) + compare + write.
// 64x32 output tile, 21.4 KB LDS -> 7 blocks/CU.
// Horizontal pass: shared-window max (10 reads + 15 fmax per 4 outputs).
// Vertical pass: row-paired — rows (2p,2p+1) share max(h[2p+1..2p+6]).
__global__ void __launch_bounds__(256)
nms_kernel(const float* __restrict__ x, float* __restrict__ out,
           const uint32_t* __restrict__ state) {
    __shared__ float t_lds[ROWS_T][LDSW];        // 38 x 76
    __shared__ float h_lds[ROWS_T][TILE_W + 1];  // 38 x 65
    float med = unmap_f32(state[0]);

    int plane = blockIdx.z;
    int tr0 = blockIdx.y * TILE_H;
    int tc0 = blockIdx.x * TILE_W;
    const float* px = x + (size_t)plane * HH * WW;
    float* pout = out + (size_t)plane * HH * WW;
    int tid = threadIdx.x;

    bool interior = (blockIdx.x >= 1) && (blockIdx.x <= (WW / TILE_W) - 2) &&
                    (blockIdx.y >= 1) && (blockIdx.y <= (HH / TILE_H) - 2);
    if (interior) {
        const float4* pv = (const float4*)(px + (size_t)(tr0 - 3) * WW + (tc0 - 4));
        for (int i = tid; i < ROWS_T * 18; i += 256) {
            int r = i / 18, v = i - r * 18;
            float4 d = pv[(size_t)r * (WW / 4) + v];
            int c = v * 4;
            t_lds[r][c + 0] = (d.x < med) ? 0.f : d.x;
            t_lds[r][c + 1] = (d.y < med) ? 0.f : d.y;
            t_lds[r][c + 2] = (d.z < med) ? 0.f : d.z;
            t_lds[r][c + 3] = (d.w < med) ? 0.f : d.w;
        }
    } else {
        for (int i = tid; i < ROWS_T * 72; i += 256) {
            int r = i / 72, c = i - r * 72;
            int gr = tr0 - 3 + r, gc = tc0 - 4 + c;
            float vv = -INFINITY;
            if (gr >= 0 && gr < HH && gc >= 0 && gc < WW) {
                float xv = px[(size_t)gr * WW + gc];
                vv = (xv < med) ? 0.f : xv;
            }
            t_lds[r][c] = vv;
        }
    }
    __syncthreads();

    // Horizontal 7-max, 4 outputs per item with shared mid = max(t[3..6]).
    for (int i = tid; i < ROWS_T * 16; i += 256) {
        int r = i >> 4, c4 = (i & 15) * 4;
        float t[10];
        #pragma unroll
        for (int j = 0; j < 10; ++j) t[j] = t_lds[r][c4 + 1 + j];
        float mid = fmaxf(fmaxf(t[3], t[4]), fmaxf(t[5], t[6]));
        h_lds[r][c4 + 0] = fmaxf(fmaxf(t[0], t[1]), fmaxf(t[2], mid));
        h_lds[r][c4 + 1] = fmaxf(fmaxf(t[1], t[2]), fmaxf(t[7], mid));
        h_lds[r][c4 + 2] = fmaxf(fmaxf(t[2], t[7]), fmaxf(t[8], mid));
        h_lds[r][c4 + 3] = fmaxf(fmaxf(t[7], t[8]), fmaxf(t[9], mid));
    }
    __syncthreads();

    // Vertical 7-max, row-paired + compare vs thresholded center + NT stores.
    for (int i = tid; i < (TILE_H / 2) * (TILE_W / 4); i += 256) {
        int pr = i >> 4, c4 = (i & 15) * 4;
        int r0 = pr * 2;
        float sh0 = h_lds[r0 + 1][c4 + 0];
        float sh1 = h_lds[r0 + 1][c4 + 1];
        float sh2 = h_lds[r0 + 1][c4 + 2];
        float sh3 = h_lds[r0 + 1][c4 + 3];
        #pragma unroll
        for (int j = 2; j <= 6; ++j) {
            sh0 = fmaxf(sh0, h_lds[r0 + j][c4 + 0]);
            sh1 = fmaxf(sh1, h_lds[r0 + j][c4 + 1]);
            sh2 = fmaxf(sh2, h_lds[r0 + j][c4 + 2]);
            sh3 = fmaxf(sh3, h_lds[r0 + j][c4 + 3]);
        }
        float a0 = fmaxf(sh0, h_lds[r0][c4 + 0]);
        float a1 = fmaxf(sh1, h_lds[r0][c4 + 1]);
        float a2 = fmaxf(sh2, h_lds[r0][c4 + 2]);
        float a3 = fmaxf(sh3, h_lds[r0][c4 + 3]);
        float b0 = fmaxf(sh0, h_lds[r0 + 7][c4 + 0]);
        float b1 = fmaxf(sh1, h_lds[r0 + 7][c4 + 1]);
        float b2 = fmaxf(sh2, h_lds[r0 + 7][c4 + 2]);
        float b3 = fmaxf(sh3, h_lds[r0 + 7][c4 + 3]);

        // row r0
        float t0 = t_lds[r0 + 3][c4 + 4], t1 = t_lds[r0 + 3][c4 + 5];
        float t2 = t_lds[r0 + 3][c4 + 6], t3 = t_lds[r0 + 3][c4 + 7];
        f4v o;
        o.x = (a0 == t0 && t0 != 0.f) ? t0 : 0.f;
        o.y = (a1 == t1 && t1 != 0.f) ? t1 : 0.f;
        o.z = (a2 == t2 && t2 != 0.f) ? t2 : 0.f;
        o.w = (a3 == t3 && t3 != 0.f) ? t3 : 0.f;
        __builtin_nontemporal_store(o, (f4v*)(pout + (size_t)(tr0 + r0) * WW + (tc0 + c4)));

        // row r0+1
        t0 = t_lds[r0 + 4][c4 + 4]; t1 = t_lds[r0 + 4][c4 + 5];
        t2 = t_lds[r0 + 4][c4 + 6]; t3 = t_lds[r0 + 4][c4 + 7];
        o.x = (b0 == t0 && t0 != 0.f) ? t0 : 0.f;
        o.y = (b1 == t1 && t1 != 0.f) ? t1 : 0.f;
        o.z = (b2 == t2 && t2 != 0.f) ? t2 : 0.f;
        o.w = (b3 == t3 && t3 != 0.f) ? t3 : 0.f;
        __builtin_nontemporal_store(o, (f4v*)(pout + (size_t)(tr0 + r0 + 1) * WW + (tc0 + c4)));
    }
}

extern "C" void kernel_launch(void* const* d_in, const int* in_sizes, int n_in,
                              void* d_out, int out_size, void* d_ws, size_t ws_size,
                              hipStream_t stream) {
    const float* x = (const float*)d_in[0];
    float* out = (float*)d_out;
    int n = in_sizes[0];                    // 8388608
    uint32_t* hist = (uint32_t*)d_ws;       // 4096*16 u32 (slot-major spread)
    uint32_t* state = hist + MAXBINS * HSPREAD;  // 8 u32
    uint32_t* cand = state + 8;             // candidates (mapped u32)
    uint32_t k = (uint32_t)((n - 1) / 2);
    int nvec = n / 4;

    init_kernel<<<(MAXBINS * HSPREAD + 255) / 256, 256, 0, stream>>>(hist, state, k);
    hist_kernel<<<HIST_GRID, HIST_BLOCK, 0, stream>>>((const uint4*)x, nvec, hist);
    select_kernel<<<1, 256, 0, stream>>>(hist, state);
    compact_kernel<<<COMP_GRID, HIST_BLOCK, 0, stream>>>((const uint4*)x, nvec, cand, state);
    final_select_kernel<<<1, 1024, 0, stream>>>(cand, state);

    int nplanes = n / (HH * WW);            // 2
    dim3 grid(WW / TILE_W, HH / TILE_H, nplanes);
    nms_kernel<<<grid, 256, 0, stream>>>(x, out, state);
}